// Round 3
// baseline (11311.184 us; speedup 1.0000x reference)
//
#include <hip/hip_runtime.h>
#include <math.h>

typedef __attribute__((ext_vector_type(8))) short sv8;
typedef __attribute__((ext_vector_type(4))) float fv4;
typedef unsigned short u16;
typedef unsigned int u32;
typedef unsigned long long u64;

#define HD   384
#define NP   1536
#define TDIM 192
#define SEQP 448
#define NBLK 256
#define NPHASE 194

// ---- ws byte offsets ----
#define OFF_B0HI  0u
#define OFF_B0LO  1179648u
#define OFF_B1AHI 2359296u
#define OFF_B1ALO 3538944u
#define OFF_B1BHI 4718592u
#define OFF_B1BLO 5898240u
#define OFF_WP    7077888u    // [384][1536] f32 rank-1 input cols
#define OFF_U     9437184u    // [192][1536] f32
#define OFF_B0P   10616832u   // [1536] f32
#define OFF_B1P   10622976u   // [1536] f32
#define OFF_H0    10629120u   // 2 x [448][384] u32 (hi | lo<<16)
#define HBUF      688128u
#define OFF_H1    12005376u
#define OFF_ZA    13381632u   // 2 x [24][7][4][64][16] f32
#define ZABUF     2752512u
#define OFF_YP    18886656u   // [192][448][24] f32
#define OFF_YY    27144192u   // [448][192] f32
#define OFF_BAR   27488256u

__device__ __forceinline__ u16 f2bf(float v) {
  unsigned u = __builtin_bit_cast(unsigned, v);
  return (u16)((u + 0x7fffu + ((u >> 16) & 1u)) >> 16);
}
__device__ __forceinline__ float bf2f(u16 s) {
  unsigned u = ((unsigned)s) << 16;
  return __builtin_bit_cast(float, u);
}
__device__ __forceinline__ float sigm(float v) { return 1.0f / (1.0f + expf(-v)); }

// ---------------- prep kernels ----------------

// Pack three K=384 weight matrices (B0=Whh0, B1a=Wih1, B1b=Whh1) into split-bf16
// fragment layout: elem (k-row j, col n) at ((j>>3)*1536 + n)*8 + (j&7);
// n = (hk/16)*64 + gate*16 + (hk%16), source row = gate*384 + hk.
__global__ void pack_weights(const float* __restrict__ W_ih, const float* __restrict__ W_hh,
                             char* __restrict__ wsb) {
  const int idx = blockIdx.x * 256 + threadIdx.x;
  const int NE = 384 * 1536;
  if (idx >= 3 * NE) return;
  const int mat = idx / NE, rem0 = idx % NE;
  const int j = rem0 / 1536, n = rem0 % 1536;
  const int q = n >> 6, rem = n & 63, g = rem >> 4, kl = rem & 15;
  const int hk = q * 16 + kl;
  const int nr = g * 384 + hk;
  float v;
  u16 *dhi, *dlo;
  if (mat == 0) {
    v = W_hh[(size_t)nr * 384 + j];
    dhi = (u16*)(wsb + OFF_B0HI); dlo = (u16*)(wsb + OFF_B0LO);
  } else if (mat == 1) {
    v = W_ih[589824 + (size_t)nr * 384 + j];
    dhi = (u16*)(wsb + OFF_B1AHI); dlo = (u16*)(wsb + OFF_B1ALO);
  } else {
    v = W_hh[589824 + (size_t)nr * 384 + j];
    dhi = (u16*)(wsb + OFF_B1BHI); dlo = (u16*)(wsb + OFF_B1BLO);
  }
  const u16 hi = f2bf(v);
  const u16 lo = f2bf(v - bf2f(hi));
  const size_t off = ((size_t)(j >> 3) * 1536 + n) * 8 + (j & 7);
  dhi[off] = hi; dlo[off] = lo;
}

__global__ void pack_aux(const float* __restrict__ W_ih, const float* __restrict__ b_ih,
                         const float* __restrict__ b_hh, char* __restrict__ wsb) {
  const int idx = blockIdx.x * 256 + threadIdx.x;
  float* Wp = (float*)(wsb + OFF_WP);
  if (idx < 384 * 1536) {
    const int seq = idx / 1536, n = idx % 1536;
    const int q = n >> 6, rem = n & 63, g = rem >> 4, kl = rem & 15;
    const int hk = q * 16 + kl;
    Wp[idx] = W_ih[(size_t)(g * 384 + hk) * 384 + seq];
  }
  if (idx < 1536) {
    const int q = idx >> 6, rem = idx & 63, g = rem >> 4, kl = rem & 15;
    const int nr = g * 384 + (q * 16 + kl);
    ((float*)(wsb + OFF_B0P))[idx] = b_ih[nr] + b_hh[nr];
    ((float*)(wsb + OFF_B1P))[idx] = b_ih[1536 + nr] + b_hh[1536 + nr];
  }
}

__global__ __launch_bounds__(256) void compute_U(const float* __restrict__ x,
                                                 char* __restrict__ wsb) {
  const float* Wp = (const float*)(wsb + OFF_WP);
  float* U = (float*)(wsb + OFF_U);
  __shared__ float xs[384];
  const int t = blockIdx.x;
  for (int j = threadIdx.x; j < 384; j += 256) xs[j] = x[(size_t)j * TDIM + t];
  __syncthreads();
  for (int n = threadIdx.x; n < 1536; n += 256) {
    float a = 0.0f;
    for (int j = 0; j < 384; ++j) a = fmaf(xs[j], Wp[(size_t)j * NP + n], a);
    U[(size_t)t * NP + n] = a;
  }
}

// ---------------- main persistent kernel ----------------

__device__ __forceinline__ void load_a(sv8 ah[12], sv8 al[12], const u32* __restrict__ plane,
                                       int rowA, int lkc) {
  const u32* base = plane + (size_t)rowA * HD + lkc * 8;
  #pragma unroll
  for (int kc = 0; kc < 12; ++kc) {
    const u64* p = (const u64*)(base + kc * 32);
    u64 q0 = __hip_atomic_load(p + 0, __ATOMIC_RELAXED, __HIP_MEMORY_SCOPE_SYSTEM);
    u64 q1 = __hip_atomic_load(p + 1, __ATOMIC_RELAXED, __HIP_MEMORY_SCOPE_SYSTEM);
    u64 q2 = __hip_atomic_load(p + 2, __ATOMIC_RELAXED, __HIP_MEMORY_SCOPE_SYSTEM);
    u64 q3 = __hip_atomic_load(p + 3, __ATOMIC_RELAXED, __HIP_MEMORY_SCOPE_SYSTEM);
    const u32 w0 = (u32)q0, w1 = (u32)(q0 >> 32), w2 = (u32)q1, w3 = (u32)(q1 >> 32);
    const u32 w4 = (u32)q2, w5 = (u32)(q2 >> 32), w6 = (u32)q3, w7 = (u32)(q3 >> 32);
    union { sv8 v; u32 w[4]; } H, L;
    H.w[0] = __builtin_amdgcn_perm(w1, w0, 0x05040100u);
    H.w[1] = __builtin_amdgcn_perm(w3, w2, 0x05040100u);
    H.w[2] = __builtin_amdgcn_perm(w5, w4, 0x05040100u);
    H.w[3] = __builtin_amdgcn_perm(w7, w6, 0x05040100u);
    L.w[0] = __builtin_amdgcn_perm(w1, w0, 0x07060302u);
    L.w[1] = __builtin_amdgcn_perm(w3, w2, 0x07060302u);
    L.w[2] = __builtin_amdgcn_perm(w5, w4, 0x07060302u);
    L.w[3] = __builtin_amdgcn_perm(w7, w6, 0x07060302u);
    ah[kc] = H.v; al[kc] = L.v;
  }
}

__device__ __forceinline__ void gemm384(fv4 acc[4], const sv8 ah[12], const sv8 al[12],
                                        const u16* __restrict__ Bhi, const u16* __restrict__ Blo,
                                        int n0, int lrow, int lkc) {
  const size_t bb = ((size_t)lkc * NP + n0 + lrow) * 8;
  #pragma unroll 4
  for (int kc = 0; kc < 12; ++kc) {
    const size_t bo = bb + (size_t)kc * 4 * NP * 8;
    #pragma unroll
    for (int g = 0; g < 4; ++g) {
      const sv8 bh = *(const sv8*)(Bhi + bo + g * 16 * 8);
      const sv8 bl = *(const sv8*)(Blo + bo + g * 16 * 8);
      acc[g] = __builtin_amdgcn_mfma_f32_16x16x32_bf16(ah[kc], bh, acc[g], 0, 0, 0);
      acc[g] = __builtin_amdgcn_mfma_f32_16x16x32_bf16(ah[kc], bl, acc[g], 0, 0, 0);
      acc[g] = __builtin_amdgcn_mfma_f32_16x16x32_bf16(al[kc], bh, acc[g], 0, 0, 0);
    }
  }
}

__global__ __launch_bounds__(256, 1) void lstm_coop(const float* __restrict__ x,
                                                    const float* __restrict__ fc_w,
                                                    char* __restrict__ wsb) {
  const u16* B0hi  = (const u16*)(wsb + OFF_B0HI);
  const u16* B0lo  = (const u16*)(wsb + OFF_B0LO);
  const u16* B1ahi = (const u16*)(wsb + OFF_B1AHI);
  const u16* B1alo = (const u16*)(wsb + OFF_B1ALO);
  const u16* B1bhi = (const u16*)(wsb + OFF_B1BHI);
  const u16* B1blo = (const u16*)(wsb + OFF_B1BLO);
  const float* Wp  = (const float*)(wsb + OFF_WP);
  const float* U   = (const float*)(wsb + OFF_U);
  const float* b0p = (const float*)(wsb + OFF_B0P);
  const float* b1p = (const float*)(wsb + OFF_B1P);
  float* Yp = (float*)(wsb + OFF_YP);
  u32* bar  = (u32*)(wsb + OFF_BAR);

  const int tid = threadIdx.x;
  const int lane = tid & 63, wv = tid >> 6;
  const int lrow = lane & 15, lkc = lane >> 4;
  const int bid = blockIdx.x;
  const int xcd = bid & 7, ib = bid >> 3;

  int s_type[2], s_kg[2], s_mt[2];
  bool s_ok[2];
  float bias4[2][4], fcw2[2], wp16[2][16];
  float cst[2][4] = {{0.f,0.f,0.f,0.f},{0.f,0.f,0.f,0.f}};
  #pragma unroll
  for (int s = 0; s < 2; ++s) {
    const int jx = ib * 2 + s;
    s_ok[s] = (jx < 63);
    const int kgl = jx < 63 ? jx / 21 : 0;
    const int rem = jx < 63 ? jx % 21 : 0;
    s_type[s] = rem / 7; s_mt[s] = rem % 7; s_kg[s] = xcd * 3 + kgl;
    const int n0 = s_kg[s] * 64;
    const float* bp = (s_type[s] == 0) ? b0p : b1p;
    #pragma unroll
    for (int g = 0; g < 4; ++g) bias4[s][g] = bp[n0 + g * 16 + lrow];
    fcw2[s] = fc_w[s_kg[s] * 16 + lrow];
    #pragma unroll
    for (int r = 0; r < 4; ++r) {
      const int seq = s_mt[s] * 64 + wv * 16 + lkc * 4 + r;
      #pragma unroll
      for (int g = 0; g < 4; ++g)
        wp16[s][r * 4 + g] = (s_type[s] == 0 && seq < 384)
                               ? Wp[(size_t)seq * NP + n0 + g * 16 + lrow] : 0.0f;
    }
  }

  for (int p = 0; p < NPHASE; ++p) {
    const u32* h0R = (const u32*)(wsb + OFF_H0 + (size_t)((p + 1) & 1) * HBUF);
    u32*       h0W = (u32*)(wsb + OFF_H0 + (size_t)(p & 1) * HBUF);
    const u32* h1R = (const u32*)(wsb + OFF_H1 + (size_t)((p + 1) & 1) * HBUF);
    u32*       h1W = (u32*)(wsb + OFF_H1 + (size_t)(p & 1) * HBUF);
    float*       zaW = (float*)(wsb + OFF_ZA + (size_t)((p + 1) & 1) * ZABUF);
    const float* zaR = (const float*)(wsb + OFF_ZA + (size_t)(p & 1) * ZABUF);

    #pragma unroll
    for (int s = 0; s < 2; ++s) {
      if (!s_ok[s]) continue;
      const int ty = s_type[s], kg = s_kg[s], mt = s_mt[s];
      const int n0 = kg * 64, seq0 = mt * 64 + wv * 16, ke = kg * 16 + lrow;
      sv8 ah[12], al[12];
      fv4 acc[4] = {{0.f,0.f,0.f,0.f},{0.f,0.f,0.f,0.f},{0.f,0.f,0.f,0.f},{0.f,0.f,0.f,0.f}};
      if (ty == 0) {
        if (p > 191) continue;
        const int t = p;
        load_a(ah, al, h0R, seq0 + lrow, lkc);
        gemm384(acc, ah, al, B0hi, B0lo, n0, lrow, lkc);
        #pragma unroll
        for (int r = 0; r < 4; ++r) {
          const int seq = seq0 + lkc * 4 + r;
          float zi = acc[0][r] + bias4[s][0], zf = acc[1][r] + bias4[s][1],
                zg = acc[2][r] + bias4[s][2], zo = acc[3][r] + bias4[s][3];
          if (seq < 384) {
            const float xv = x[(size_t)seq * TDIM + t];
            zi = fmaf(xv, wp16[s][r * 4 + 0], zi);
            zf = fmaf(xv, wp16[s][r * 4 + 1], zf);
            zg = fmaf(xv, wp16[s][r * 4 + 2], zg);
            zo = fmaf(xv, wp16[s][r * 4 + 3], zo);
          } else if (seq == 384) {
            const float* ur = U + (size_t)t * NP + n0;
            zi += ur[lrow]; zf += ur[16 + lrow]; zg += ur[32 + lrow]; zo += ur[48 + lrow];
          }
          const float ig = sigm(zi), fg = sigm(zf), gv = tanhf(zg), og = sigm(zo);
          const float cn = fg * cst[s][r] + ig * gv;
          cst[s][r] = cn;
          const float h = og * tanhf(cn);
          const u16 hh = f2bf(h); const u16 hl = f2bf(h - bf2f(hh));
          __hip_atomic_store(h0W + (size_t)seq * HD + ke, (u32)hh | ((u32)hl << 16),
                             __ATOMIC_RELAXED, __HIP_MEMORY_SCOPE_SYSTEM);
        }
      } else if (ty == 1) {
        if (p < 1 || p > 192) continue;
        load_a(ah, al, h0R, seq0 + lrow, lkc);
        gemm384(acc, ah, al, B1ahi, B1alo, n0, lrow, lkc);
        float* zb = zaW + ((((size_t)kg * 7 + mt) * 4 + wv) * 64 + lane) * 16;
        #pragma unroll
        for (int g = 0; g < 4; ++g) {
          #pragma unroll
          for (int r = 0; r < 4; r += 2) {
            const float v0 = acc[g][r] + bias4[s][g];
            const float v1 = acc[g][r + 1] + bias4[s][g];
            const u64 q = (u64)__builtin_bit_cast(u32, v0) |
                          ((u64)__builtin_bit_cast(u32, v1) << 32);
            __hip_atomic_store((u64*)(zb + g * 4 + r), q,
                               __ATOMIC_RELAXED, __HIP_MEMORY_SCOPE_SYSTEM);
          }
        }
      } else {
        if (p < 2) continue;
        const int t = p - 2;
        load_a(ah, al, h1R, seq0 + lrow, lkc);
        gemm384(acc, ah, al, B1bhi, B1blo, n0, lrow, lkc);
        const float* zb = zaR + ((((size_t)kg * 7 + mt) * 4 + wv) * 64 + lane) * 16;
        float zv[16];
        #pragma unroll
        for (int i2 = 0; i2 < 8; ++i2) {
          const u64 q = __hip_atomic_load((const u64*)(zb + i2 * 2),
                                          __ATOMIC_RELAXED, __HIP_MEMORY_SCOPE_SYSTEM);
          zv[i2 * 2]     = __builtin_bit_cast(float, (u32)q);
          zv[i2 * 2 + 1] = __builtin_bit_cast(float, (u32)(q >> 32));
        }
        #pragma unroll
        for (int r = 0; r < 4; ++r) {
          const int seq = seq0 + lkc * 4 + r;
          const float zi = acc[0][r] + zv[r],      zf = acc[1][r] + zv[4 + r],
                      zg = acc[2][r] + zv[8 + r],  zo = acc[3][r] + zv[12 + r];
          const float ig = sigm(zi), fg = sigm(zf), gv = tanhf(zg), og = sigm(zo);
          const float cn = fg * cst[s][r] + ig * gv;
          cst[s][r] = cn;
          const float h = og * tanhf(cn);
          const u16 hh = f2bf(h); const u16 hl = f2bf(h - bf2f(hh));
          __hip_atomic_store(h1W + (size_t)seq * HD + ke, (u32)hh | ((u32)hl << 16),
                             __ATOMIC_RELAXED, __HIP_MEMORY_SCOPE_SYSTEM);
          float yv = h * fcw2[s];
          yv += __shfl_xor(yv, 1); yv += __shfl_xor(yv, 2);
          yv += __shfl_xor(yv, 4); yv += __shfl_xor(yv, 8);
          if (lrow == 0) Yp[((size_t)t * SEQP + seq) * 24 + kg] = yv;
        }
      }
    }
    // ---- lightweight global barrier (no cache writeback/invalidate) ----
    __syncthreads();
    if (tid == 0) {
      __hip_atomic_fetch_add(bar, 1u, __ATOMIC_RELAXED, __HIP_MEMORY_SCOPE_SYSTEM);
      const u32 tgt = (u32)NBLK * (u32)(p + 1);
      while (__hip_atomic_load(bar, __ATOMIC_RELAXED, __HIP_MEMORY_SCOPE_SYSTEM) < tgt)
        __builtin_amdgcn_s_sleep(1);
    }
    __syncthreads();
  }
}

// ---------------- epilogue kernels ----------------

__global__ void y_final(const float* __restrict__ fc_b, char* __restrict__ wsb) {
  const float* Yp = (const float*)(wsb + OFF_YP);
  float* Y = (float*)(wsb + OFF_YY);
  const int t = blockIdx.x;
  const int seq = threadIdx.x;
  if (seq < 385) {
    const float* p = Yp + ((size_t)t * SEQP + seq) * 24;
    float s = fc_b[0];
    #pragma unroll
    for (int k = 0; k < 24; ++k) s += p[k];
    Y[(size_t)seq * TDIM + t] = s;
  }
}

__global__ void copy_yi(char* __restrict__ wsb, float* __restrict__ out) {
  const float* Y = (const float*)(wsb + OFF_YY);
  const int i = blockIdx.x * 256 + threadIdx.x;
  if (i < 384 * 192) out[192 + i] = Y[i];
}

__global__ __launch_bounds__(384) void attn_final(char* __restrict__ wsb,
                                                  float* __restrict__ out) {
  const float* Y = (const float*)(wsb + OFF_YY);
  __shared__ float sc[384];
  __shared__ float redm[8], reds[8];
  const int j = threadIdx.x;
  const float* ya = Y + (size_t)384 * TDIM;
  float dot = 0.f;
  for (int t = 0; t < TDIM; ++t) dot = fmaf(ya[t], Y[(size_t)j * TDIM + t], dot);
  float m = dot;
  m = fmaxf(m, __shfl_xor(m, 32)); m = fmaxf(m, __shfl_xor(m, 16));
  m = fmaxf(m, __shfl_xor(m, 8));  m = fmaxf(m, __shfl_xor(m, 4));
  m = fmaxf(m, __shfl_xor(m, 2));  m = fmaxf(m, __shfl_xor(m, 1));
  if ((j & 63) == 0) redm[j >> 6] = m;
  __syncthreads();
  float M = redm[0];
  #pragma unroll
  for (int w = 1; w < 6; ++w) M = fmaxf(M, redm[w]);
  const float e = expf(dot - M);
  float ss = e;
  ss += __shfl_xor(ss, 32); ss += __shfl_xor(ss, 16); ss += __shfl_xor(ss, 8);
  ss += __shfl_xor(ss, 4);  ss += __shfl_xor(ss, 2);  ss += __shfl_xor(ss, 1);
  if ((j & 63) == 0) reds[j >> 6] = ss;
  __syncthreads();
  float S = 0.f;
  #pragma unroll
  for (int w = 0; w < 6; ++w) S += reds[w];
  const float a = e / S;
  sc[j] = a;
  out[192 + 73728 + j] = a;
  __syncthreads();
  if (j < 192) {
    float acc = 0.f;
    for (int jj = 0; jj < 384; ++jj) acc = fmaf(sc[jj], Y[(size_t)jj * TDIM + j], acc);
    out[j] = acc;
  }
}

extern "C" void kernel_launch(void* const* d_in, const int* in_sizes, int n_in,
                              void* d_out, int out_size, void* d_ws, size_t ws_size,
                              hipStream_t stream) {
  const float* x    = (const float*)d_in[0];
  const float* W_ih = (const float*)d_in[1];
  const float* W_hh = (const float*)d_in[2];
  const float* b_ih = (const float*)d_in[3];
  const float* b_hh = (const float*)d_in[4];
  const float* fc_w = (const float*)d_in[5];
  const float* fc_b = (const float*)d_in[6];
  float* out = (float*)d_out;
  char* wsb  = (char*)d_ws;

  hipMemsetAsync(wsb + OFF_H0, 0, 2 * HBUF * 2, stream);   // h0 + h1 (both parities)
  hipMemsetAsync(wsb + OFF_BAR, 0, 64, stream);
  hipLaunchKernelGGL(pack_weights, dim3(6912), dim3(256), 0, stream, W_ih, W_hh, wsb);
  hipLaunchKernelGGL(pack_aux,     dim3(2304), dim3(256), 0, stream, W_ih, b_ih, b_hh, wsb);
  hipLaunchKernelGGL(compute_U,    dim3(192),  dim3(256), 0, stream, x, wsb);

  void* args[] = {(void*)&x, (void*)&fc_w, (void*)&wsb};
  hipLaunchCooperativeKernel((void*)lstm_coop, dim3(NBLK), dim3(256), args, 0, stream);

  hipLaunchKernelGGL(y_final,  dim3(192), dim3(448), 0, stream, fc_b, wsb);
  hipLaunchKernelGGL(copy_yi,  dim3(288), dim3(256), 0, stream, wsb, out);
  hipLaunchKernelGGL(attn_final, dim3(1), dim3(384), 0, stream, wsb, out);
}

// Round 5
// 8497.324 us; speedup vs baseline: 1.3311x; 1.3311x over previous
//
#include <hip/hip_runtime.h>
#include <math.h>

typedef __attribute__((ext_vector_type(8))) short sv8;
typedef __attribute__((ext_vector_type(4))) float fv4;
typedef unsigned short u16;
typedef unsigned int u32;
typedef unsigned long long u64;

#define HD   384
#define NP   1536
#define TDIM 192
#define SEQP 448
#define NBLK 256
#define NPHASE 194

// ---- ws byte offsets ----
#define OFF_B0HI  0u
#define OFF_B0LO  1179648u
#define OFF_B1AHI 2359296u
#define OFF_B1ALO 3538944u
#define OFF_B1BHI 4718592u
#define OFF_B1BLO 5898240u
#define OFF_WP    7077888u    // [384][1536] f32 rank-1 input cols
#define OFF_U     9437184u    // [192][1536] f32
#define OFF_B0P   10616832u   // [1536] f32
#define OFF_B1P   10622976u   // [1536] f32
#define OFF_H0    10629120u   // 2 x [448][384] u32 (hi | lo<<16)
#define HBUF      688128u
#define OFF_H1    12005376u
#define OFF_ZA    13381632u   // 2 x [672 jobwv][4][64][4] f32 (lane-interleaved)
#define ZABUF     2752512u
#define OFF_YP    18886656u   // [192][448][24] f32
#define OFF_YY    27144192u   // [448][192] f32
#define OFF_BAR   27488256u   // arr[256] u32, padded to 64 B/slot (16 KB)

__device__ __forceinline__ u16 f2bf(float v) {
  unsigned u = __builtin_bit_cast(unsigned, v);
  return (u16)((u + 0x7fffu + ((u >> 16) & 1u)) >> 16);
}
__device__ __forceinline__ float bf2f(u16 s) {
  unsigned u = ((unsigned)s) << 16;
  return __builtin_bit_cast(float, u);
}
__device__ __forceinline__ float sigm(float v) { return 1.0f / (1.0f + expf(-v)); }

__device__ __forceinline__ void store16_sc(float* p, fv4 v) {
  asm volatile("global_store_dwordx4 %0, %1, off sc0 sc1"
               :: "v"(p), "v"(v) : "memory");
}
__device__ __forceinline__ fv4 load16_sc(const float* p) {
  fv4 r;
  asm volatile("global_load_dwordx4 %0, %1, off sc0 sc1"
               : "=v"(r) : "v"(p) : "memory");
  return r;
}

// ---------------- prep kernels ----------------

__global__ void pack_weights(const float* __restrict__ W_ih, const float* __restrict__ W_hh,
                             char* __restrict__ wsb) {
  const int idx = blockIdx.x * 256 + threadIdx.x;
  const int NE = 384 * 1536;
  if (idx >= 3 * NE) return;
  const int mat = idx / NE, rem0 = idx % NE;
  const int j = rem0 / 1536, n = rem0 % 1536;
  const int q = n >> 6, rem = n & 63, g = rem >> 4, kl = rem & 15;
  const int hk = q * 16 + kl;
  const int nr = g * 384 + hk;
  float v;
  u16 *dhi, *dlo;
  if (mat == 0) {
    v = W_hh[(size_t)nr * 384 + j];
    dhi = (u16*)(wsb + OFF_B0HI); dlo = (u16*)(wsb + OFF_B0LO);
  } else if (mat == 1) {
    v = W_ih[589824 + (size_t)nr * 384 + j];
    dhi = (u16*)(wsb + OFF_B1AHI); dlo = (u16*)(wsb + OFF_B1ALO);
  } else {
    v = W_hh[589824 + (size_t)nr * 384 + j];
    dhi = (u16*)(wsb + OFF_B1BHI); dlo = (u16*)(wsb + OFF_B1BLO);
  }
  const u16 hi = f2bf(v);
  const u16 lo = f2bf(v - bf2f(hi));
  const size_t off = ((size_t)(j >> 3) * 1536 + n) * 8 + (j & 7);
  dhi[off] = hi; dlo[off] = lo;
}

__global__ void pack_aux(const float* __restrict__ W_ih, const float* __restrict__ b_ih,
                         const float* __restrict__ b_hh, char* __restrict__ wsb) {
  const int idx = blockIdx.x * 256 + threadIdx.x;
  float* Wp = (float*)(wsb + OFF_WP);
  if (idx < 384 * 1536) {
    const int seq = idx / 1536, n = idx % 1536;
    const int q = n >> 6, rem = n & 63, g = rem >> 4, kl = rem & 15;
    const int hk = q * 16 + kl;
    Wp[idx] = W_ih[(size_t)(g * 384 + hk) * 384 + seq];
  }
  if (idx < 1536) {
    const int q = idx >> 6, rem = idx & 63, g = rem >> 4, kl = rem & 15;
    const int nr = g * 384 + (q * 16 + kl);
    ((float*)(wsb + OFF_B0P))[idx] = b_ih[nr] + b_hh[nr];
    ((float*)(wsb + OFF_B1P))[idx] = b_ih[1536 + nr] + b_hh[1536 + nr];
  }
}

__global__ __launch_bounds__(256) void compute_U(const float* __restrict__ x,
                                                 char* __restrict__ wsb) {
  const float* Wp = (const float*)(wsb + OFF_WP);
  float* U = (float*)(wsb + OFF_U);
  __shared__ float xs[384];
  const int t = blockIdx.x;
  for (int j = threadIdx.x; j < 384; j += 256) xs[j] = x[(size_t)j * TDIM + t];
  __syncthreads();
  for (int n = threadIdx.x; n < 1536; n += 256) {
    float a = 0.0f;
    for (int j = 0; j < 384; ++j) a = fmaf(xs[j], Wp[(size_t)j * NP + n], a);
    U[(size_t)t * NP + n] = a;
  }
}

// ---------------- main persistent kernel ----------------

__device__ __forceinline__ void load_a(sv8 ah[12], sv8 al[12], const u32* __restrict__ plane,
                                       int rowA, int lkc) {
  const u32* base = plane + (size_t)rowA * HD + lkc * 8;
  #pragma unroll
  for (int kc = 0; kc < 12; ++kc) {
    const u64* p = (const u64*)(base + kc * 32);
    u64 q0 = __hip_atomic_load(p + 0, __ATOMIC_RELAXED, __HIP_MEMORY_SCOPE_SYSTEM);
    u64 q1 = __hip_atomic_load(p + 1, __ATOMIC_RELAXED, __HIP_MEMORY_SCOPE_SYSTEM);
    u64 q2 = __hip_atomic_load(p + 2, __ATOMIC_RELAXED, __HIP_MEMORY_SCOPE_SYSTEM);
    u64 q3 = __hip_atomic_load(p + 3, __ATOMIC_RELAXED, __HIP_MEMORY_SCOPE_SYSTEM);
    const u32 w0 = (u32)q0, w1 = (u32)(q0 >> 32), w2 = (u32)q1, w3 = (u32)(q1 >> 32);
    const u32 w4 = (u32)q2, w5 = (u32)(q2 >> 32), w6 = (u32)q3, w7 = (u32)(q3 >> 32);
    union { sv8 v; u32 w[4]; } H, L;
    H.w[0] = __builtin_amdgcn_perm(w1, w0, 0x05040100u);
    H.w[1] = __builtin_amdgcn_perm(w3, w2, 0x05040100u);
    H.w[2] = __builtin_amdgcn_perm(w5, w4, 0x05040100u);
    H.w[3] = __builtin_amdgcn_perm(w7, w6, 0x05040100u);
    L.w[0] = __builtin_amdgcn_perm(w1, w0, 0x07060302u);
    L.w[1] = __builtin_amdgcn_perm(w3, w2, 0x07060302u);
    L.w[2] = __builtin_amdgcn_perm(w5, w4, 0x07060302u);
    L.w[3] = __builtin_amdgcn_perm(w7, w6, 0x07060302u);
    ah[kc] = H.v; al[kc] = L.v;
  }
}

__device__ __forceinline__ void gemm384(fv4 acc[4], const sv8 ah[12], const sv8 al[12],
                                        const u16* __restrict__ Bhi, const u16* __restrict__ Blo,
                                        int n0, int lrow, int lkc) {
  const size_t bb = ((size_t)lkc * NP + n0 + lrow) * 8;
  #pragma unroll 4
  for (int kc = 0; kc < 12; ++kc) {
    const size_t bo = bb + (size_t)kc * 4 * NP * 8;
    #pragma unroll
    for (int g = 0; g < 4; ++g) {
      const sv8 bh = *(const sv8*)(Bhi + bo + g * 16 * 8);
      const sv8 bl = *(const sv8*)(Blo + bo + g * 16 * 8);
      acc[g] = __builtin_amdgcn_mfma_f32_16x16x32_bf16(ah[kc], bh, acc[g], 0, 0, 0);
      acc[g] = __builtin_amdgcn_mfma_f32_16x16x32_bf16(ah[kc], bl, acc[g], 0, 0, 0);
      acc[g] = __builtin_amdgcn_mfma_f32_16x16x32_bf16(al[kc], bh, acc[g], 0, 0, 0);
    }
  }
}

__global__ __launch_bounds__(256, 1) void lstm_coop(const float* __restrict__ x,
                                                    const float* __restrict__ fc_w,
                                                    char* __restrict__ wsb) {
  const u16* B0hi  = (const u16*)(wsb + OFF_B0HI);
  const u16* B0lo  = (const u16*)(wsb + OFF_B0LO);
  const u16* B1ahi = (const u16*)(wsb + OFF_B1AHI);
  const u16* B1alo = (const u16*)(wsb + OFF_B1ALO);
  const u16* B1bhi = (const u16*)(wsb + OFF_B1BHI);
  const u16* B1blo = (const u16*)(wsb + OFF_B1BLO);
  const float* Wp  = (const float*)(wsb + OFF_WP);
  const float* U   = (const float*)(wsb + OFF_U);
  const float* b0p = (const float*)(wsb + OFF_B0P);
  const float* b1p = (const float*)(wsb + OFF_B1P);
  float* Yp = (float*)(wsb + OFF_YP);
  u32* arr  = (u32*)(wsb + OFF_BAR);

  const int tid = threadIdx.x;
  const int lane = tid & 63, wv = tid >> 6;
  const int lrow = lane & 15, lkc = lane >> 4;
  const int bid = blockIdx.x;
  const int xcd = bid & 7, ib = bid >> 3;

  int s_type[2], s_kg[2], s_mt[2];
  bool s_ok[2];
  float bias4[2][4], fcw2[2], wp16[2][16];
  float cst[2][4] = {{0.f,0.f,0.f,0.f},{0.f,0.f,0.f,0.f}};
  #pragma unroll
  for (int s = 0; s < 2; ++s) {
    const int jx = ib * 2 + s;
    s_ok[s] = (jx < 63);
    const int kgl = jx < 63 ? jx / 21 : 0;
    const int rem = jx < 63 ? jx % 21 : 0;
    s_type[s] = rem / 7; s_mt[s] = rem % 7; s_kg[s] = xcd * 3 + kgl;
    const int n0 = s_kg[s] * 64;
    const float* bp = (s_type[s] == 0) ? b0p : b1p;
    #pragma unroll
    for (int g = 0; g < 4; ++g) bias4[s][g] = bp[n0 + g * 16 + lrow];
    fcw2[s] = fc_w[s_kg[s] * 16 + lrow];
    #pragma unroll
    for (int r = 0; r < 4; ++r) {
      const int seq = s_mt[s] * 64 + wv * 16 + lkc * 4 + r;
      #pragma unroll
      for (int g = 0; g < 4; ++g)
        wp16[s][r * 4 + g] = (s_type[s] == 0 && seq < 384)
                               ? Wp[(size_t)seq * NP + n0 + g * 16 + lrow] : 0.0f;
    }
  }

  for (int p = 0; p < NPHASE; ++p) {
    const u32* h0R = (const u32*)(wsb + OFF_H0 + (size_t)((p + 1) & 1) * HBUF);
    u32*       h0W = (u32*)(wsb + OFF_H0 + (size_t)(p & 1) * HBUF);
    const u32* h1R = (const u32*)(wsb + OFF_H1 + (size_t)((p + 1) & 1) * HBUF);
    u32*       h1W = (u32*)(wsb + OFF_H1 + (size_t)(p & 1) * HBUF);
    float*       zaW = (float*)(wsb + OFF_ZA + (size_t)((p + 1) & 1) * ZABUF);
    const float* zaR = (const float*)(wsb + OFF_ZA + (size_t)(p & 1) * ZABUF);

    #pragma unroll
    for (int s = 0; s < 2; ++s) {
      if (!s_ok[s]) continue;
      const int ty = s_type[s], kg = s_kg[s], mt = s_mt[s];
      const int n0 = kg * 64, seq0 = mt * 64 + wv * 16, ke = kg * 16 + lrow;
      sv8 ah[12], al[12];
      fv4 acc[4] = {{0.f,0.f,0.f,0.f},{0.f,0.f,0.f,0.f},{0.f,0.f,0.f,0.f},{0.f,0.f,0.f,0.f}};
      if (ty == 0) {
        if (p > 191) continue;
        const int t = p;
        load_a(ah, al, h0R, seq0 + lrow, lkc);
        gemm384(acc, ah, al, B0hi, B0lo, n0, lrow, lkc);
        #pragma unroll
        for (int r = 0; r < 4; ++r) {
          const int seq = seq0 + lkc * 4 + r;
          float zi = acc[0][r] + bias4[s][0], zf = acc[1][r] + bias4[s][1],
                zg = acc[2][r] + bias4[s][2], zo = acc[3][r] + bias4[s][3];
          if (seq < 384) {
            const float xv = x[(size_t)seq * TDIM + t];
            zi = fmaf(xv, wp16[s][r * 4 + 0], zi);
            zf = fmaf(xv, wp16[s][r * 4 + 1], zf);
            zg = fmaf(xv, wp16[s][r * 4 + 2], zg);
            zo = fmaf(xv, wp16[s][r * 4 + 3], zo);
          } else if (seq == 384) {
            const float* ur = U + (size_t)t * NP + n0;
            zi += ur[lrow]; zf += ur[16 + lrow]; zg += ur[32 + lrow]; zo += ur[48 + lrow];
          }
          const float ig = sigm(zi), fg = sigm(zf), gv = tanhf(zg), og = sigm(zo);
          const float cn = fg * cst[s][r] + ig * gv;
          cst[s][r] = cn;
          const float h = og * tanhf(cn);
          const u16 hh = f2bf(h); const u16 hl = f2bf(h - bf2f(hh));
          __hip_atomic_store(h0W + (size_t)seq * HD + ke, (u32)hh | ((u32)hl << 16),
                             __ATOMIC_RELAXED, __HIP_MEMORY_SCOPE_SYSTEM);
        }
      } else if (ty == 1) {
        if (p < 1 || p > 192) continue;
        load_a(ah, al, h0R, seq0 + lrow, lkc);
        gemm384(acc, ah, al, B1ahi, B1alo, n0, lrow, lkc);
        // za: lane-interleaved coalesced layout [jobwv][g][lane][4]
        float* zb = zaW + (((size_t)kg * 7 + mt) * 4 + wv) * 1024;
        #pragma unroll
        for (int g = 0; g < 4; ++g) {
          fv4 zc;
          #pragma unroll
          for (int r = 0; r < 4; ++r) zc[r] = acc[g][r] + bias4[s][g];
          store16_sc(zb + g * 256 + lane * 4, zc);
        }
      } else {
        if (p < 2) continue;
        const int t = p - 2;
        load_a(ah, al, h1R, seq0 + lrow, lkc);
        gemm384(acc, ah, al, B1bhi, B1blo, n0, lrow, lkc);
        const float* zb = zaR + (((size_t)kg * 7 + mt) * 4 + wv) * 1024;
        fv4 zv4[4];
        zv4[0] = load16_sc(zb + 0 * 256 + lane * 4);
        zv4[1] = load16_sc(zb + 1 * 256 + lane * 4);
        zv4[2] = load16_sc(zb + 2 * 256 + lane * 4);
        zv4[3] = load16_sc(zb + 3 * 256 + lane * 4);
        asm volatile("s_waitcnt vmcnt(0)" ::: "memory");
        __builtin_amdgcn_sched_barrier(0);
        #pragma unroll
        for (int r = 0; r < 4; ++r) {
          const int seq = seq0 + lkc * 4 + r;
          const float zi = acc[0][r] + zv4[0][r], zf = acc[1][r] + zv4[1][r],
                      zg = acc[2][r] + zv4[2][r], zo = acc[3][r] + zv4[3][r];
          const float ig = sigm(zi), fg = sigm(zf), gv = tanhf(zg), og = sigm(zo);
          const float cn = fg * cst[s][r] + ig * gv;
          cst[s][r] = cn;
          const float h = og * tanhf(cn);
          const u16 hh = f2bf(h); const u16 hl = f2bf(h - bf2f(hh));
          __hip_atomic_store(h1W + (size_t)seq * HD + ke, (u32)hh | ((u32)hl << 16),
                             __ATOMIC_RELAXED, __HIP_MEMORY_SCOPE_SYSTEM);
          float yv = h * fcw2[s];
          yv += __shfl_xor(yv, 1); yv += __shfl_xor(yv, 2);
          yv += __shfl_xor(yv, 4); yv += __shfl_xor(yv, 8);
          if (lrow == 0) Yp[((size_t)t * SEQP + seq) * 24 + kg] = yv;
        }
      }
    }
    // ---- symmetric flag barrier: each block publishes its own padded slot;
    //      every thread polls exactly one block's slot (monotonic counters).
    __syncthreads();   // all waves drain their stores (implicit vmcnt(0) per wave)
    if (tid == 0)
      __hip_atomic_store(&arr[(size_t)bid * 16], (u32)(p + 1),
                         __ATOMIC_RELAXED, __HIP_MEMORY_SCOPE_SYSTEM);
    {
      const u32 tgt = (u32)(p + 1);
      while (__hip_atomic_load(&arr[(size_t)tid * 16],
                               __ATOMIC_RELAXED, __HIP_MEMORY_SCOPE_SYSTEM) < tgt)
        __builtin_amdgcn_s_sleep(2);
    }
    __syncthreads();
  }
}

// ---------------- epilogue kernels ----------------

__global__ void y_final(const float* __restrict__ fc_b, char* __restrict__ wsb) {
  const float* Yp = (const float*)(wsb + OFF_YP);
  float* Y = (float*)(wsb + OFF_YY);
  const int t = blockIdx.x;
  const int seq = threadIdx.x;
  if (seq < 385) {
    const float* p = Yp + ((size_t)t * SEQP + seq) * 24;
    float s = fc_b[0];
    #pragma unroll
    for (int k = 0; k < 24; ++k) s += p[k];
    Y[(size_t)seq * TDIM + t] = s;
  }
}

__global__ void copy_yi(char* __restrict__ wsb, float* __restrict__ out) {
  const float* Y = (const float*)(wsb + OFF_YY);
  const int i = blockIdx.x * 256 + threadIdx.x;
  if (i < 384 * 192) out[192 + i] = Y[i];
}

__global__ __launch_bounds__(384) void attn_final(char* __restrict__ wsb,
                                                  float* __restrict__ out) {
  const float* Y = (const float*)(wsb + OFF_YY);
  __shared__ float sc[384];
  __shared__ float redm[8], reds[8];
  const int j = threadIdx.x;
  const float* ya = Y + (size_t)384 * TDIM;
  float dot = 0.f;
  for (int t = 0; t < TDIM; ++t) dot = fmaf(ya[t], Y[(size_t)j * TDIM + t], dot);
  float m = dot;
  m = fmaxf(m, __shfl_xor(m, 32)); m = fmaxf(m, __shfl_xor(m, 16));
  m = fmaxf(m, __shfl_xor(m, 8));  m = fmaxf(m, __shfl_xor(m, 4));
  m = fmaxf(m, __shfl_xor(m, 2));  m = fmaxf(m, __shfl_xor(m, 1));
  if ((j & 63) == 0) redm[j >> 6] = m;
  __syncthreads();
  float M = redm[0];
  #pragma unroll
  for (int w = 1; w < 6; ++w) M = fmaxf(M, redm[w]);
  const float e = expf(dot - M);
  float ss = e;
  ss += __shfl_xor(ss, 32); ss += __shfl_xor(ss, 16); ss += __shfl_xor(ss, 8);
  ss += __shfl_xor(ss, 4);  ss += __shfl_xor(ss, 2);  ss += __shfl_xor(ss, 1);
  if ((j & 63) == 0) reds[j >> 6] = ss;
  __syncthreads();
  float S = 0.f;
  #pragma unroll
  for (int w = 0; w < 6; ++w) S += reds[w];
  const float a = e / S;
  sc[j] = a;
  out[192 + 73728 + j] = a;
  __syncthreads();
  if (j < 192) {
    float acc = 0.f;
    for (int jj = 0; jj < 384; ++jj) acc = fmaf(sc[jj], Y[(size_t)jj * TDIM + j], acc);
    out[j] = acc;
  }
}

extern "C" void kernel_launch(void* const* d_in, const int* in_sizes, int n_in,
                              void* d_out, int out_size, void* d_ws, size_t ws_size,
                              hipStream_t stream) {
  const float* x    = (const float*)d_in[0];
  const float* W_ih = (const float*)d_in[1];
  const float* W_hh = (const float*)d_in[2];
  const float* b_ih = (const float*)d_in[3];
  const float* b_hh = (const float*)d_in[4];
  const float* fc_w = (const float*)d_in[5];
  const float* fc_b = (const float*)d_in[6];
  float* out = (float*)d_out;
  char* wsb  = (char*)d_ws;

  hipMemsetAsync(wsb + OFF_H0, 0, 2 * HBUF * 2, stream);   // h0 + h1 (both parities)
  hipMemsetAsync(wsb + OFF_BAR, 0, 16384, stream);         // padded arrival slots
  hipLaunchKernelGGL(pack_weights, dim3(6912), dim3(256), 0, stream, W_ih, W_hh, wsb);
  hipLaunchKernelGGL(pack_aux,     dim3(2304), dim3(256), 0, stream, W_ih, b_ih, b_hh, wsb);
  hipLaunchKernelGGL(compute_U,    dim3(192),  dim3(256), 0, stream, x, wsb);

  void* args[] = {(void*)&x, (void*)&fc_w, (void*)&wsb};
  hipLaunchCooperativeKernel((void*)lstm_coop, dim3(NBLK), dim3(256), args, 0, stream);

  hipLaunchKernelGGL(y_final,  dim3(192), dim3(448), 0, stream, fc_b, wsb);
  hipLaunchKernelGGL(copy_yi,  dim3(288), dim3(256), 0, stream, wsb, out);
  hipLaunchKernelGGL(attn_final, dim3(1), dim3(384), 0, stream, wsb, out);
}